// Round 1
// baseline (170.079 us; speedup 1.0000x reference)
//
#include <hip/hip_runtime.h>
#include <hip/hip_bf16.h>

// Problem constants (fixed by the reference setup)
#define N_ROWS   500000
#define NR1      25        // nr + 1
#define NGROUPS  20000     // N_ROWS / NR1
#define KCTX     20        // K context indices
#define H        128
#define NODES    10000
#define IDX_COLS 23        // 3 + K

#define RPB      128       // rows per k_main block (1 tile, TLP instead of ILP pipeline)
#define MAXG     7         // max ctx groups spanned by 128 rows (127/25 straddle + 1)

typedef __attribute__((ext_vector_type(8))) short short8;   // 8 bf16 = 4 VGPRs
typedef __attribute__((ext_vector_type(4))) float f32x4;    // MFMA C/D

// pack two floats -> two bf16 (RNE) as a 32-bit word
__device__ __forceinline__ unsigned pkbf(float lo, float hi) {
  __hip_bfloat162 h = __float22bfloat162_rn(make_float2(lo, hi));
  union { __hip_bfloat162 h; unsigned u; } c; c.h = h;
  return c.u;
}
__device__ __forceinline__ float bf2f(unsigned short u) {
  union { unsigned u; float f; } c; c.u = ((unsigned)u) << 16; return c.f;
}

// ---------------------------------------------------------------------------
// Kernel A (v5): fused precompute + index pack (unchanged).
//  y = 0..2 : P[m] = x @ W1m.T via bf16 MFMA, P stored bf16
//  y = 3    : grid-stride (i0,i1) -> idx2 pack (concurrent with y=0..2)
// ---------------------------------------------------------------------------
#define PN 64
#define PRE_BLOCKS ((NODES + PN - 1) / PN)   // 157
__global__ __launch_bounds__(256) void k_precompute(
    const float* __restrict__ x, const float* __restrict__ W1,
    const int* __restrict__ indices,
    unsigned short* __restrict__ Pb, int2* __restrict__ idx2) {
  const int tid = threadIdx.x;
  const int m   = blockIdx.y;

  if (m == 3) {
    const int stride = PRE_BLOCKS * 256;
    for (int r = blockIdx.x * 256 + tid; r < N_ROWS; r += stride) {
      idx2[r] = make_int2(indices[(size_t)r * IDX_COLS + 0],
                          indices[(size_t)r * IDX_COLS + 1]);
    }
    return;
  }

  __shared__ short wlds[128][136];   // bf16 W1m[j][k], padded: 34.8 KB
  const int tbase = blockIdx.x * PN;

#pragma unroll
  for (int it = 0; it < 16; ++it) {
    const int f  = it * 256 + tid;
    const int j  = f >> 5;
    const int q4 = f & 31;
    const float4 v = *(const float4*)(W1 + (size_t)j * (3 * H) + m * H + q4 * 4);
    *(unsigned*)&wlds[j][q4 * 4]     = pkbf(v.x, v.y);
    *(unsigned*)&wlds[j][q4 * 4 + 2] = pkbf(v.z, v.w);
  }
  __syncthreads();

  const int lane = tid & 63;
  const int wv   = tid >> 6;
  const int col  = lane & 15;
  const int quad = lane >> 4;

  int node = tbase + wv * 16 + col;
  if (node > NODES - 1) node = NODES - 1;
  const float4* __restrict__ xr = (const float4*)(x + (size_t)node * H);

  short8 Af[4];
#pragma unroll
  for (int kt = 0; kt < 4; ++kt) {
    const int f4 = kt * 8 + quad * 2;
    const float4 v0 = xr[f4], v1 = xr[f4 + 1];
    union { short8 v; unsigned u[4]; } pk;
    pk.u[0] = pkbf(v0.x, v0.y);
    pk.u[1] = pkbf(v0.z, v0.w);
    pk.u[2] = pkbf(v1.x, v1.y);
    pk.u[3] = pkbf(v1.z, v1.w);
    Af[kt] = pk.v;
  }

  f32x4 acc[8];
#pragma unroll
  for (int ct = 0; ct < 8; ++ct) acc[ct] = (f32x4)(0.f);

#pragma unroll
  for (int kt = 0; kt < 4; ++kt) {
#pragma unroll
    for (int ct = 0; ct < 8; ++ct) {
      const short8 Bf = *(const short8*)&wlds[ct * 16 + col][kt * 32 + quad * 8];
      acc[ct] = __builtin_amdgcn_mfma_f32_16x16x32_bf16(Af[kt], Bf, acc[ct], 0, 0, 0);
    }
  }

  unsigned short* __restrict__ Pm = Pb + (size_t)m * NODES * H;
#pragma unroll
  for (int reg = 0; reg < 4; ++reg) {
    const int n = tbase + wv * 16 + quad * 4 + reg;
    if (n < NODES) {
#pragma unroll
      for (int ct = 0; ct < 8; ++ct) {
        union { unsigned u; unsigned short s[2]; } c;
        c.u = pkbf(acc[ct][reg], 0.f);
        Pm[(size_t)n * H + ct * 16 + col] = c.s[0];
      }
    }
  }
}

// ---------------------------------------------------------------------------
// Kernel C (v12): SINGLE-tile main kernel, 128 rows/block, 3907 blocks.
//  Rationale: v11 (512 rows/block, 4-tile intra-wave pipeline) was
//  latency-bound at 3.8 waves/SIMD of total work (Occupancy 24%). v12 trades
//  the intra-wave pipeline for 4x the blocks (15.3 waves/SIMD of work) so TLP
//  hides gather latency. Per-wave ILP is retained by issuing the P1/P2
//  gathers FIRST, before W2 staging + ctx phase (~independent work covering
//  the L2 round-trip), consumed only after the barrier.
//   Phase -1: issue idx2 load + P1/P2 gathers (no LDS dependency)
//   Phase 0a: W2 -> LDS bf16
//   Phase 0b: <=7 ctx-group rows -> cgs (2 iterations of 4 groups)
//   ONE barrier, then A-build -> MFMA layer 2 -> epilogue -> store
// ---------------------------------------------------------------------------
__global__ __launch_bounds__(256) void k_main(
    const int* __restrict__ indices, const int2* __restrict__ idx2,
    const unsigned short* __restrict__ P1b, const unsigned short* __restrict__ P2b,
    const unsigned short* __restrict__ P3b,
    const float* __restrict__ W2, const float* __restrict__ b1,
    const float* __restrict__ b2, const float* __restrict__ W3,
    const float* __restrict__ b3, float* __restrict__ out) {
  __shared__ short w2s[64][136];      // bf16 W2[n][k], padded: 17.4 KB
  __shared__ float cgs[MAXG][132];    // ctx rows (b1 folded), padded: 3.7 KB

  const int tid   = threadIdx.x;
  const int rbase = blockIdx.x * RPB;
  const int gbase = rbase / NR1;

  const int lane = tid & 63;
  const int wv   = tid >> 6;
  const int col  = lane & 15;
  const int quad = lane >> 4;

  // ---- phase -1: issue gathers for this block's rows (in flight across
  //      phase 0; lands before the barrier's lgkm/vm drain) ----
  short8 ua[2][4], ub[2][4];
  int    gl[2];
  {
    const int R = rbase + wv * 32;
#pragma unroll
    for (int rt = 0; rt < 2; ++rt) {
      const int r  = R + rt * 16 + col;
      const int rc = (r < N_ROWS) ? r : (N_ROWS - 1);
      const int2 ii = idx2[rc];
      const short8* __restrict__ pa = (const short8*)(P1b + (size_t)ii.x * H);
      const short8* __restrict__ pb = (const short8*)(P2b + (size_t)ii.y * H);
#pragma unroll
      for (int kt = 0; kt < 4; ++kt) {
        ua[rt][kt] = pa[kt * 4 + quad];
        ub[rt][kt] = pb[kt * 4 + quad];
      }
      gl[rt] = rc / NR1 - gbase;
    }
  }

  // ---- phase 0a: W2 -> LDS bf16 (coalesced float2 reads, L2-resident) ----
  for (int idx = tid; idx < 64 * 64; idx += 256) {
    const int n  = idx >> 6;
    const int kp = idx & 63;
    const float2 w = *(const float2*)(W2 + (size_t)n * H + kp * 2);
    *(unsigned*)&w2s[n][kp * 2] = pkbf(w.x, w.y);
  }

  // ---- phase 0b: ctx groups (<=7), 4 per iteration, u32 P3 reads ----
  {
    int rlast = rbase + RPB - 1; if (rlast > N_ROWS - 1) rlast = N_ROWS - 1;
    const int G   = rlast / NR1 - gbase + 1;   // <= 7
    const int jj  = (tid & 63) * 2;
    const int sub = tid >> 6;
    const float2 b1v = *(const float2*)(b1 + jj);
#pragma unroll
    for (int it = 0; it < 2; ++it) {
      const int gi = it * 4 + sub;
      if (gi < G) {
        const int* __restrict__ rowidx =
            indices + (size_t)(gbase + gi) * NR1 * IDX_COLS + 3;  // wave-uniform
        float s0 = 0.f, s1 = 0.f;
        int cnt = 0;
#pragma unroll
        for (int c = 0; c < KCTX; ++c) {
          const int idx = rowidx[c];
          const unsigned w = *(const unsigned*)(P3b + (size_t)idx * H + jj);
          s0 += bf2f((unsigned short)(w & 0xffffu));
          s1 += bf2f((unsigned short)(w >> 16));
          cnt += (idx > 0) ? 1 : 0;
        }
        const float rn = 1.f / (float)((cnt > 1) ? cnt : 1);
        cgs[gi][jj]     = b1v.x + s0 * rn;
        cgs[gi][jj + 1] = b1v.y + s1 * rn;
      }
    }
  }
  __syncthreads();

  // epilogue constants (L1-hot, load once)
  float b2v[4], w3v[4];
#pragma unroll
  for (int ct = 0; ct < 4; ++ct) {
    b2v[ct] = b2[ct * 16 + col];
    w3v[ct] = W3[ct * 16 + col];
  }
  const float bias3 = b3[0];

  // ---- A-build: relu(P1[i0] + P2[i1] + ctx) -> bf16 fragments ----
  short8 A[2][4];
#pragma unroll
  for (int rt = 0; rt < 2; ++rt) {
#pragma unroll
    for (int kt = 0; kt < 4; ++kt) {
      union { short8 v; unsigned short s[8]; } va, vb;
      va.v = ua[rt][kt];
      vb.v = ub[rt][kt];
      const float4 c0 = *(const float4*)&cgs[gl[rt]][kt * 32 + quad * 8];
      const float4 c1 = *(const float4*)&cgs[gl[rt]][kt * 32 + quad * 8 + 4];
      const float h0 = fmaxf(bf2f(va.s[0]) + bf2f(vb.s[0]) + c0.x, 0.f);
      const float h1 = fmaxf(bf2f(va.s[1]) + bf2f(vb.s[1]) + c0.y, 0.f);
      const float h2 = fmaxf(bf2f(va.s[2]) + bf2f(vb.s[2]) + c0.z, 0.f);
      const float h3 = fmaxf(bf2f(va.s[3]) + bf2f(vb.s[3]) + c0.w, 0.f);
      const float h4 = fmaxf(bf2f(va.s[4]) + bf2f(vb.s[4]) + c1.x, 0.f);
      const float h5 = fmaxf(bf2f(va.s[5]) + bf2f(vb.s[5]) + c1.y, 0.f);
      const float h6 = fmaxf(bf2f(va.s[6]) + bf2f(vb.s[6]) + c1.z, 0.f);
      const float h7 = fmaxf(bf2f(va.s[7]) + bf2f(vb.s[7]) + c1.w, 0.f);
      union { short8 v; unsigned u[4]; } pk;
      pk.u[0] = pkbf(h0, h1);
      pk.u[1] = pkbf(h2, h3);
      pk.u[2] = pkbf(h4, h5);
      pk.u[3] = pkbf(h6, h7);
      A[rt][kt] = pk.v;
    }
  }

  // ---- MFMA layer 2 + epilogue + store ----
  f32x4 acc[2][4];
#pragma unroll
  for (int rt = 0; rt < 2; ++rt)
#pragma unroll
    for (int ct = 0; ct < 4; ++ct) acc[rt][ct] = (f32x4)(0.f);
#pragma unroll
  for (int kt = 0; kt < 4; ++kt) {
#pragma unroll
    for (int ct = 0; ct < 4; ++ct) {
      const short8 Bf = *(const short8*)&w2s[ct * 16 + col][kt * 32 + quad * 8];
#pragma unroll
      for (int rt = 0; rt < 2; ++rt)
        acc[rt][ct] = __builtin_amdgcn_mfma_f32_16x16x32_bf16(
            A[rt][kt], Bf, acc[rt][ct], 0, 0, 0);
    }
  }

  const int Rt = rbase + wv * 32;
#pragma unroll
  for (int rt = 0; rt < 2; ++rt) {
#pragma unroll
    for (int reg = 0; reg < 4; ++reg) {
      float s = 0.f;
#pragma unroll
      for (int ct = 0; ct < 4; ++ct)
        s += fmaxf(acc[rt][ct][reg] + b2v[ct], 0.f) * w3v[ct];
      s += __shfl_xor(s, 1);
      s += __shfl_xor(s, 2);
      s += __shfl_xor(s, 4);
      s += __shfl_xor(s, 8);
      if (col == 0) {
        const int row = Rt + rt * 16 + quad * 4 + reg;   // C row = quad*4+reg
        if (row < N_ROWS) out[row] = s + bias3;
      }
    }
  }
}

// ---------------------------------------------------------------------------
extern "C" void kernel_launch(void* const* d_in, const int* in_sizes, int n_in,
                              void* d_out, int out_size, void* d_ws, size_t ws_size,
                              hipStream_t stream) {
  const int*   indices = (const int*)  d_in[0];
  // d_in[1] = nr (scalar, fixed at 24)
  const float* x  = (const float*)d_in[2];
  const float* W1 = (const float*)d_in[3];
  const float* b1 = (const float*)d_in[4];
  const float* W2 = (const float*)d_in[5];
  const float* b2 = (const float*)d_in[6];
  const float* W3 = (const float*)d_in[7];
  const float* b3 = (const float*)d_in[8];
  float* out = (float*)d_out;

  // Workspace: Pb (bf16 7.68 MB) | idx2 (4 MB)
  unsigned short* Pb  = (unsigned short*)d_ws;
  unsigned short* P1b = Pb;
  unsigned short* P2b = Pb + (size_t)NODES * H;
  unsigned short* P3b = Pb + (size_t)2 * NODES * H;
  int2* idx2 = (int2*)(Pb + (size_t)3 * NODES * H);

  dim3 gpre(PRE_BLOCKS, 4);   // y=0..2: P slices, y=3: idx pack (concurrent)
  k_precompute<<<gpre, 256, 0, stream>>>(x, W1, indices, Pb, idx2);
  k_main<<<(N_ROWS + RPB - 1) / RPB, 256, 0, stream>>>(indices, idx2,
                                                       P1b, P2b, P3b,
                                                       W2, b1, b2, W3, b3, out);
}